// Round 9
// baseline (7257.865 us; speedup 1.0000x reference)
//
#include <hip/hip_runtime.h>
#include <hip/hip_bf16.h>
#include <math.h>

typedef unsigned short u16;
typedef unsigned int   u32;
typedef unsigned long long u64;
typedef __attribute__((ext_vector_type(8))) short short8;
typedef __attribute__((ext_vector_type(4))) float float4v;

#define BB 64
#define SS 512

// bf16 helpers (RNE)
__device__ __forceinline__ u16 f2b(float f) {
    u32 x = __float_as_uint(f);
    u32 r = (x + 0x7fffu + ((x >> 16) & 1u)) >> 16;
    return (u16)r;
}
__device__ __forceinline__ float b2f(u32 lo16) { return __uint_as_float(lo16 << 16); }
__device__ __forceinline__ float b2fh(u32 v)   { return __uint_as_float(v & 0xffff0000u); }

// ---------------------------------------------------------------------------
__global__ __launch_bounds__(256) void zero_kernel(float* __restrict__ p, int n) {
    int i = blockIdx.x * 256 + threadIdx.x;
    if (i < n) p[i] = 0.f;
}

// ---------------------------------------------------------------------------
__global__ __launch_bounds__(256) void pe_kernel(float* __restrict__ pe) {
    int s = blockIdx.x, j = threadIdx.x;
    float ang = (float)s * powf(10000.0f, -(2.0f * (float)j) / 512.0f);
    pe[s * 512 + 2 * j]     = sinf(ang);
    pe[s * 512 + 2 * j + 1] = cosf(ang);
}

// ---------------------------------------------------------------------------
// fp32 [R][C] -> bf16 [C][R]
// ---------------------------------------------------------------------------
__global__ __launch_bounds__(256) void transp_w(const float* __restrict__ in,
                                                u16* __restrict__ out, int R, int C) {
    __shared__ float t[64][65];
    int r0 = blockIdx.x * 64, c0 = blockIdx.y * 64;
    int tid = threadIdx.x;
    int lr = tid >> 4, lc4 = (tid & 15) * 4;
#pragma unroll
    for (int i = 0; i < 4; i++) {
        int r = lr + i * 16;
        float4 v = *(const float4*)(in + (long)(r0 + r) * C + c0 + lc4);
        t[r][lc4] = v.x; t[r][lc4 + 1] = v.y; t[r][lc4 + 2] = v.z; t[r][lc4 + 3] = v.w;
    }
    __syncthreads();
#pragma unroll
    for (int i = 0; i < 4; i++) {
        int c = lr + i * 16;
        u32 lo = (u32)f2b(t[lc4][c])     | ((u32)f2b(t[lc4 + 1][c]) << 16);
        u32 hi = (u32)f2b(t[lc4 + 2][c]) | ((u32)f2b(t[lc4 + 3][c]) << 16);
        uint2 pk; pk.x = lo; pk.y = hi;
        *(uint2*)(out + (long)(c0 + c) * R + r0 + lc4) = pk;
    }
}

// ---------------------------------------------------------------------------
__global__ __launch_bounds__(256) void cvt_bf16(const float* __restrict__ in,
                                                u16* __restrict__ out, long n) {
    long i = (long)blockIdx.x * 256 + threadIdx.x;
    if (i < n) out[i] = f2b(in[i]);
}

// ---------------------------------------------------------------------------
// bf16 [nb][R][C(ldin)] -> out[b][c][r] with element strides
// ---------------------------------------------------------------------------
__global__ __launch_bounds__(256) void transp_b(const u16* __restrict__ in,
                                                u16* __restrict__ out,
                                                int R, int C, int ldin,
                                                long sbin, long sb, long sc) {
    __shared__ u32 t[64][65];
    int bz = blockIdx.z;
    in += (long)bz * sbin;
    int r0 = blockIdx.x * 64, c0 = blockIdx.y * 64;
    int tid = threadIdx.x;
    int lr = tid >> 4, lc4 = (tid & 15) * 4;
#pragma unroll
    for (int i = 0; i < 4; i++) {
        int r = lr + i * 16;
        uint2 v = *(const uint2*)(in + (long)(r0 + r) * ldin + c0 + lc4);
        t[r][lc4] = v.x & 0xffffu; t[r][lc4 + 1] = v.x >> 16;
        t[r][lc4 + 2] = v.y & 0xffffu; t[r][lc4 + 3] = v.y >> 16;
    }
    __syncthreads();
#pragma unroll
    for (int i = 0; i < 4; i++) {
        int c = lr + i * 16;
        uint2 pk;
        pk.x = t[lc4][c] | (t[lc4 + 1][c] << 16);
        pk.y = t[lc4 + 2][c] | (t[lc4 + 3][c] << 16);
        *(uint2*)(out + (long)bz * sb + (long)(c0 + c) * sc + r0 + lc4) = pk;
    }
}

// ---------------------------------------------------------------------------
__global__ __launch_bounds__(256) void embed_kernel(
    const int* __restrict__ cate, const float* __restrict__ cont,
    const float* __restrict__ emb, const float* __restrict__ Wc,
    const float* __restrict__ bc, u16* __restrict__ xc, int gbase)
{
    long bs = (long)gbase + blockIdx.x;
    long r  = blockIdx.x;
    __shared__ float cf[6];
    if (threadIdx.x < 6) cf[threadIdx.x] = cont[bs * 6 + threadIdx.x];
    __syncthreads();
    for (int h = threadIdx.x; h < 1024; h += 256) {
        float v;
        if (h < 512) {
            int c = h >> 7, e = h & 127;
            int idx = cate[bs * 4 + c];
            v = emb[((long)c * 1000 + idx) * 128 + e];
        } else {
            int hh = h - 512;
            v = bc[hh];
#pragma unroll
            for (int f = 0; f < 6; f++) v += cf[f] * Wc[f * 512 + hh];
        }
        xc[r * 1024 + h] = f2b(v);
    }
}

// ---------------------------------------------------------------------------
// bf16 MFMA NT GEMM (validated: absmax 0.0)
// ---------------------------------------------------------------------------
__global__ __launch_bounds__(256) void gemm_nt(
    const u16* __restrict__ A, const u16* __restrict__ B, void* __restrict__ Cv,
    int K, int lda, int ldb, int ldc,
    long sA, long sB, long sC,
    const float* __restrict__ bias, const float* __restrict__ pe,
    float alpha, int outBf16)
{
    __shared__ u16 As[128][40];
    __shared__ u16 Bs[128][40];

    A += (long)blockIdx.z * sA;
    B += (long)blockIdx.z * sB;
    int m0 = blockIdx.y * 128, n0 = blockIdx.x * 128;
    int tid = threadIdx.x;
    int lane = tid & 63, wid = tid >> 6;
    int wm = (wid >> 1) * 64, wn = (wid & 1) * 64;
    int mrow = lane & 15, q8 = (lane >> 4) * 8;

    float4v acc[4][4];
#pragma unroll
    for (int i = 0; i < 4; i++)
#pragma unroll
        for (int j = 0; j < 4; j++) { float4v z = {0.f, 0.f, 0.f, 0.f}; acc[i][j] = z; }

    for (int k0 = 0; k0 < K; k0 += 32) {
        {
            int r = tid >> 2, sg = tid & 3;
            *(short8*)&As[r][sg * 8] = *(const short8*)(A + (long)(m0 + r) * lda + k0 + sg * 8);
            *(short8*)&Bs[r][sg * 8] = *(const short8*)(B + (long)(n0 + r) * ldb + k0 + sg * 8);
            r = (tid + 256) >> 2;
            *(short8*)&As[r][sg * 8] = *(const short8*)(A + (long)(m0 + r) * lda + k0 + sg * 8);
            *(short8*)&Bs[r][sg * 8] = *(const short8*)(B + (long)(n0 + r) * ldb + k0 + sg * 8);
        }
        __syncthreads();
        short8 af[4], bfr[4];
#pragma unroll
        for (int t = 0; t < 4; t++) {
            af[t]  = *(const short8*)&As[wm + t * 16 + mrow][q8];
            bfr[t] = *(const short8*)&Bs[wn + t * 16 + mrow][q8];
        }
#pragma unroll
        for (int i = 0; i < 4; i++)
#pragma unroll
            for (int j = 0; j < 4; j++)
                acc[i][j] = __builtin_amdgcn_mfma_f32_16x16x32_bf16(af[i], bfr[j], acc[i][j], 0, 0, 0);
        __syncthreads();
    }

    int col = lane & 15, quad = lane >> 4;
    u16*  Cb = (u16*)Cv  + (outBf16 ? (long)blockIdx.z * sC : 0);
    float* Cf = (float*)Cv + (outBf16 ? 0 : (long)blockIdx.z * sC);
#pragma unroll
    for (int i = 0; i < 4; i++)
#pragma unroll
        for (int j = 0; j < 4; j++) {
#pragma unroll
            for (int rr = 0; rr < 4; rr++) {
                int gm = m0 + wm + i * 16 + quad * 4 + rr;
                int gn = n0 + wn + j * 16 + col;
                float v = acc[i][j][rr] * alpha;
                if (bias) v += bias[gn];
                if (pe)   v += pe[(long)(gm & 511) * 512 + gn];
                if (outBf16) Cb[(long)gm * ldc + gn] = f2b(v);
                else         Cf[(long)gm * ldc + gn] = v;
            }
        }
}

// ---------------------------------------------------------------------------
// Softmax over QUERY axis fp32 -> bf16
// ---------------------------------------------------------------------------
__global__ __launch_bounds__(64) void softmax_q(const float* __restrict__ S,
                                                u16* __restrict__ P) {
    int b = blockIdx.x;
    int k = blockIdx.y * 64 + threadIdx.x;
    const float* p = S + (long)b * 262144 + k;
    u16* o = P + (long)b * 262144 + k;
    float m = -1e30f;
    for (int q = 0; q < 512; q++) m = fmaxf(m, p[(long)q * 512]);
    float sum = 0.f;
    for (int q = 0; q < 512; q++) sum += expf(p[(long)q * 512] - m);
    float inv = 1.f / sum;
    for (int q = 0; q < 512; q++) o[(long)q * 512] = f2b(expf(p[(long)q * 512] - m) * inv);
}

// ---------------------------------------------------------------------------
// R9: LAYER-FUSED pipelined MFMA GRU. 256 blocks x 512 thr (8 waves):
//   lyr = blk>>7, bg = blk&7 (XCD under round-robin), us = (blk>>3)&15.
// Layer-0 group bg and layer-1 group bg share an XCD -> producer/consumer
// visibility is same-L2 (fast, per R7). Layer 0 = R8 structure (gi0 from
// precomputed buffer, Wh regs, tag+spin hx exchange) + publishes per-(bg,us)
// progress flag after barrier A (compiler's vmcnt(0)-before-s_barrier drains
// prior h1bf stores — R6-validated pattern). Layer 1 polls the 16 L0 flags
// (ACQUIRE, forbids x1-load hoisting), stages x1 from h1bf (first-touch
// reads), computes gi1 = x1 @ Wi1^T IN-KERNEL via MFMA (Wi regs), then its
// own recurrent exchange. No L0->L1 wait cycle -> deadlock-free. Separate
// hx rings per layer. 8 waves: 1 MFMA tile/wave (waves 0-5), VGPR ~180 ->
// 2 waves/SIMD co-residency for 512-thr blocks. gi0 prefetch moved AFTER
// barrier A (its HBM latency was drained BY barrier A in R8).
// hx: u64[2 lyr][2 parity][8 bg][2048]; flags u32[8 bg][16 us] at +512KB.
// ---------------------------------------------------------------------------
__global__ __launch_bounds__(512, 1) void gru_fused(
    const float* __restrict__ gi0,    // [128][64][1536] fp32 (L0, this segment)
    const u16* __restrict__ Wh0, const u16* __restrict__ Wh1,
    const u16* __restrict__ Wi1,      // [1536][512] bf16 each
    const float* __restrict__ bh0, const float* __restrict__ bh1,
    const float* __restrict__ bi1,
    u16* __restrict__ h1bf, u16* __restrict__ h2bf,
    u64* __restrict__ hx, int s0)
{
    __shared__ u16 hlds[16 * 512];    // 16 KB  h A-matrix (rows 8-15 zero)
    __shared__ u16 xlds[16 * 512];    // 16 KB  x1 A-matrix (L1; rows 8-15 zero)
    __shared__ float pre[6 * 16 * 34];// 13 KB  [gate r,z,n, gi_r,gi_z,gi_n][b][u]
    __shared__ float hprev[8 * 32];   // 1 KB   own slice h fp32

    int blk = blockIdx.x;
    int lyr = blk >> 7;
    int bg  = blk & 7;
    int us  = (blk >> 3) & 15;
    int tid = threadIdx.x;
    int lane = tid & 63, wid = tid >> 6;

    u64* hxL   = hx + (long)lyr * 32768;
    u32* flags = (u32*)(hx + 65536);

    // finalize mapping (tid<128): (batch fb 0..7, unit-pair up 0..15)
    int fb = (tid >> 4) & 7, up = tid & 15;
    int u0 = up << 1;
    int ug = (us << 5) + u0;
    const float* bh_l = lyr ? bh1 : bh0;
    float2 bhr = *(const float2*)(bh_l + ug);
    float2 bhz = *(const float2*)(bh_l + 512 + ug);
    float2 bhn = *(const float2*)(bh_l + 1024 + ug);
    float2 bir = {0.f, 0.f}, biz = {0.f, 0.f}, bin = {0.f, 0.f};
    if (lyr) {
        bir = *(const float2*)(bi1 + ug);
        biz = *(const float2*)(bi1 + 512 + ug);
        bin = *(const float2*)(bi1 + 1024 + ug);
    }

    // MFMA: one tile per wave (waves 0-5)
    int t = wid;
    int bq = lane & 15, kq = (lane >> 4) << 3;
    char* hbase = (char*)hlds + (bq << 10);
    char* xbase = (char*)xlds + (bq << 10);
    int swz = (bq & 7) << 4;

    short8 brh[16], bri[16];
    if (t < 6) {
        int r_ = (t << 4) + bq;
        long grow = (long)((r_ >> 5) << 9) + (us << 5) + (r_ & 31);
        const u16* whp = (lyr ? Wh1 : Wh0) + grow * 512 + kq;
#pragma unroll
        for (int ks = 0; ks < 16; ks++) brh[ks] = *(const short8*)(whp + ks * 32);
        if (lyr) {
            const u16* wip = Wi1 + grow * 512 + kq;
#pragma unroll
            for (int ks = 0; ks < 16; ks++) bri[ks] = *(const short8*)(wip + ks * 32);
        }
    }

    // zero hlds + xlds (rows 8-15 stay zero forever)
    {
        u32* hz = (u32*)hlds;
        u32* xz = (u32*)xlds;
#pragma unroll
        for (int i = 0; i < 8; i++) { hz[tid + i * 512] = 0; xz[tid + i * 512] = 0; }
    }
    __syncthreads();

    for (int sl = 0; sl < 128; sl++) {
        int s = s0 + sl;

        // ---- L1: wait for layer-0 step s, stage x1 into xlds ----
        if (lyr) {
            u32 needv = (u32)(s + 1);
            u32* fp = flags + (bg << 4) + (lane & 15);
            int guard = 0;
            for (;;) {
                u32 f = __hip_atomic_load(fp, __ATOMIC_ACQUIRE, __HIP_MEMORY_SCOPE_AGENT);
                if (__all((int)(f - needv) >= 0)) break;
                __builtin_amdgcn_s_sleep(1);
                if (++guard > (1 << 13)) break;   // safety: never fires in correct runs
            }
            int b = tid >> 6, k8 = tid & 63;
            short8 xv = *(const short8*)(h1bf + ((long)s * 64 + (bg << 3) + b) * 512 + (k8 << 3));
            *(short8*)((char*)xlds + ((b << 10) + ((k8 << 4) ^ (b << 4)))) = xv;
        }

        // ---- gather own-layer h (skip at s==0: zero state) ----
        if (s > 0) {
            u32 exp_tag = (u32)(lyr * 512 + s);
            const u64* src = hxL + ((long)(exp_tag & 1) << 14) + ((long)bg << 11) + tid;
            u32 need = 0xfu;
            int guard = 0;
            while (need) {
                u64 v[4];
#pragma unroll
                for (int j = 0; j < 4; j++)
                    v[j] = __hip_atomic_load(src + (j << 9), __ATOMIC_RELAXED, __HIP_MEMORY_SCOPE_AGENT);
#pragma unroll
                for (int j = 0; j < 4; j++) {
                    if ((need & (1u << j)) && (u32)(v[j] >> 32) == exp_tag) {
                        int i = tid + (j << 9);
                        int b = i & 7, pr = i >> 3;
                        *(u32*)((char*)hlds + ((b << 10) + ((pr << 2) ^ (b << 4)))) = (u32)v[j];
                        need &= ~(1u << j);
                    }
                }
                if (need) {
                    __builtin_amdgcn_s_sleep(1);
                    if (++guard > (1 << 12)) break;   // safety
                }
            }
        }
        __syncthreads();   // barrier A: hlds/xlds complete; prior stores drained

        // ---- L0: publish progress (steps < s0+sl are complete & drained) ----
        if (!lyr && tid == 0)
            __hip_atomic_store(flags + (bg << 4) + us, (u32)(s0 + sl),
                               __ATOMIC_RELAXED, __HIP_MEMORY_SCOPE_AGENT);

        // ---- L0: gi0 prefetch (issued now so barrier A doesn't drain it) ----
        float2 g_r = {0.f, 0.f}, g_z = {0.f, 0.f}, g_n = {0.f, 0.f};
        if (!lyr && tid < 128) {
            const float* g = gi0 + ((long)sl * 64 + (bg << 3) + fb) * 1536 + ug;
            g_r = *(const float2*)g;
            g_z = *(const float2*)(g + 512);
            g_n = *(const float2*)(g + 1024);
        }

        // ---- segment start: restore own-slice fp32 h ----
        if (sl == 0 && tid < 128) {
            int pr = (us << 4) + up;
            u32 pk = *(u32*)((char*)hlds + ((fb << 10) + ((pr << 2) ^ (fb << 4))));
            hprev[(fb << 5) + u0]     = b2f(pk & 0xffffu);
            hprev[(fb << 5) + u0 + 1] = b2fh(pk);
        }

        // ---- MFMA: h-matvec (and L1: x-matvec for gi1) ----
        if (t < 6) {
            float4v acc = {0.f, 0.f, 0.f, 0.f};
#pragma unroll
            for (int ks = 0; ks < 16; ks++) {
                int k2 = ((ks << 5) + kq) << 1;
                short8 a = *(const short8*)(hbase + (k2 ^ swz));
                acc = __builtin_amdgcn_mfma_f32_16x16x32_bf16(a, brh[ks], acc, 0, 0, 0);
            }
            int gq = lane >> 4;
            int uu = ((t << 4) + (lane & 15)) & 31;
#pragma unroll
            for (int rr = 0; rr < 4; rr++) {
                int b = (gq << 2) + rr;
                pre[((t >> 1) * 16 + b) * 34 + uu] = acc[rr];
            }
            if (lyr) {
                float4v accx = {0.f, 0.f, 0.f, 0.f};
#pragma unroll
                for (int ks = 0; ks < 16; ks++) {
                    int k2 = ((ks << 5) + kq) << 1;
                    short8 a = *(const short8*)(xbase + (k2 ^ swz));
                    accx = __builtin_amdgcn_mfma_f32_16x16x32_bf16(a, bri[ks], accx, 0, 0, 0);
                }
#pragma unroll
                for (int rr = 0; rr < 4; rr++) {
                    int b = (gq << 2) + rr;
                    pre[((3 + (t >> 1)) * 16 + b) * 34 + uu] = accx[rr];
                }
            }
        }
        __syncthreads();   // barrier B: pre complete; LDS reads done

        // ---- finalize (tid<128); no barrier after: drains fold into next spin ----
        if (tid < 128) {
            float2 sr = *(const float2*)&pre[(0 * 16 + fb) * 34 + u0];
            float2 sz = *(const float2*)&pre[(1 * 16 + fb) * 34 + u0];
            float2 sn = *(const float2*)&pre[(2 * 16 + fb) * 34 + u0];
            if (lyr) {
                float2 xr = *(const float2*)&pre[(3 * 16 + fb) * 34 + u0];
                float2 xz = *(const float2*)&pre[(4 * 16 + fb) * 34 + u0];
                float2 xn = *(const float2*)&pre[(5 * 16 + fb) * 34 + u0];
                g_r.x = xr.x + bir.x; g_r.y = xr.y + bir.y;
                g_z.x = xz.x + biz.x; g_z.y = xz.y + biz.y;
                g_n.x = xn.x + bin.x; g_n.y = xn.y + bin.y;
            }
            float r0v = 1.f / (1.f + expf(-(g_r.x + sr.x + bhr.x)));
            float r1v = 1.f / (1.f + expf(-(g_r.y + sr.y + bhr.y)));
            float z0v = 1.f / (1.f + expf(-(g_z.x + sz.x + bhz.x)));
            float z1v = 1.f / (1.f + expf(-(g_z.y + sz.y + bhz.y)));
            float n0v = tanhf(g_n.x + r0v * (sn.x + bhn.x));
            float n1v = tanhf(g_n.y + r1v * (sn.y + bhn.y));
            float hp0 = hprev[(fb << 5) + u0];
            float hp1 = hprev[(fb << 5) + u0 + 1];
            float hn0 = (1.f - z0v) * n0v + z0v * hp0;
            float hn1 = (1.f - z1v) * n1v + z1v * hp1;
            hprev[(fb << 5) + u0]     = hn0;
            hprev[(fb << 5) + u0 + 1] = hn1;
            u16 q0 = f2b(hn0), q1 = f2b(hn1);
            u32 pk = ((u32)q1 << 16) | (u32)q0;
            u32 wt = (u32)(lyr * 512 + s + 1);
            u64 pv = ((u64)wt << 32) | (u64)pk;
            int slot = (((us << 4) + up) << 3) + fb;
            u64* dst = hxL + ((long)(wt & 1) << 14) + ((long)bg << 11) + slot;
            __hip_atomic_store(dst, pv, __ATOMIC_RELAXED, __HIP_MEMORY_SCOPE_AGENT);
            u16* so = lyr ? h2bf : h1bf;
            *(u32*)(so + ((long)s * 64 + (bg << 3) + fb) * 512 + ug) = pk;
        }
    }

    // L0: final publish so L1's last step can proceed
    if (!lyr) {
        __syncthreads();   // drains last finalize stores
        if (tid == 0)
            __hip_atomic_store(flags + (bg << 4) + us, (u32)(s0 + 128),
                               __ATOMIC_RELAXED, __HIP_MEMORY_SCOPE_AGENT);
    }
}

// ---------------------------------------------------------------------------
__global__ __launch_bounds__(256) void final_kernel(
    const u16* __restrict__ h2, const float* __restrict__ Wf,
    const float* __restrict__ bfin, float* __restrict__ out)
{
    int w = blockIdx.x * 4 + (threadIdx.x >> 6);
    int lane = threadIdx.x & 63;
    const u16* row = h2 + (long)w * 512;
    uint4 hv = *(const uint4*)(row + lane * 8);
    float4 w0 = *(const float4*)(Wf + lane * 8);
    float4 w1 = *(const float4*)(Wf + lane * 8 + 4);
    float sum = b2f(hv.x & 0xffffu) * w0.x + b2fh(hv.x) * w0.y
              + b2f(hv.y & 0xffffu) * w0.z + b2fh(hv.y) * w0.w
              + b2f(hv.z & 0xffffu) * w1.x + b2fh(hv.z) * w1.y
              + b2f(hv.w & 0xffffu) * w1.z + b2fh(hv.w) * w1.w;
#pragma unroll
    for (int off = 32; off > 0; off >>= 1) sum += __shfl_down(sum, off, 64);
    if (lane == 0) {
        int s = w >> 6, b = w & 63;
        out[(long)b * 512 + s] = 1.f / (1.f + expf(-(sum + bfin[0])));
    }
}

// ---------------------------------------------------------------------------
// Launcher — workspace ~169.4 MB. Phase-3 aliasing (all dead after phase 2):
// h2bf NOW at ws+117440512 (over QKV/Vt/Sg/Pg/zT — NOT over zp, which L0's
// gi GEMMs still read during the fused overlap); hx at ws+150994944 (xc).
// ---------------------------------------------------------------------------
extern "C" void kernel_launch(void* const* d_in, const int* in_sizes, int n_in,
                              void* d_out, int out_size, void* d_ws, size_t ws_size,
                              hipStream_t stream) {
    const int*   cate  = (const int*)  d_in[0];
    const float* cont  = (const float*)d_in[1];
    const float* emb   = (const float*)d_in[4];
    const float* Wc    = (const float*)d_in[5];
    const float* bc    = (const float*)d_in[6];
    const float* Wcomb = (const float*)d_in[7];
    const float* bcomb = (const float*)d_in[8];
    const float* Wq    = (const float*)d_in[9];
    const float* Wk    = (const float*)d_in[10];
    const float* Wv    = (const float*)d_in[11];
    const float* Wi    = (const float*)d_in[12];
    const float* Wh    = (const float*)d_in[13];
    const float* bi    = (const float*)d_in[14];
    const float* bh    = (const float*)d_in[15];
    const float* Wf    = (const float*)d_in[16];
    const float* bfin  = (const float*)d_in[17];
    float* out = (float*)d_out;
    char* ws = (char*)d_ws;

    u16*   zp    = (u16*)(ws + 0);
    u16*   h1bf  = (u16*)(ws + 33554432);
    float* gi    = (float*)(ws + 67108864);   // 50.3 MB, aliases xbf
    u16*   xbf   = (u16*)(ws + 67108864);
    u16*   QKV   = (u16*)(ws + 117440512);    // [4096][1536] bf16 = 12.58 MB
    u16*   h2bf  = (u16*)(ws + 117440512);    // phase-3: 33.5 MB over QKV..zT
    u16*   Vt    = (u16*)(ws + 130023424);
    float* Sg    = (float*)(ws + 134217728);  // phase-2 only
    u16*   Pg    = (u16*)(ws + 142606336);
    u16*   zT    = (u16*)(ws + 146800640);
    u16*   xc    = (u16*)(ws + 150994944);
    u64*   hx    = (u64*)  (ws + 150994944);  // phase-3: 525 KB over xc
    u16*   WcombT= (u16*)(ws + 159383552);
    u16*   WqT   = (u16*)(ws + 160432128);    // contiguous: WqT|WkT|WvT = [1536][512]
    u16*   WkT   = (u16*)(ws + 160956416);
    u16*   WvT   = (u16*)(ws + 161480704);
    u16*   WiB   = (u16*)(ws + 162004992);
    float* pe    = (float*)(ws + 165150720);
    u16*   WhB   = (u16*)(ws + 166199296);    // [2][1536][512] bf16 = 3.15 MB

    transp_w<<<dim3(16, 8), 256, 0, stream>>>(Wcomb, WcombT, 1024, 512);
    transp_w<<<dim3(8, 8),  256, 0, stream>>>(Wq, WqT, 512, 512);
    transp_w<<<dim3(8, 8),  256, 0, stream>>>(Wk, WkT, 512, 512);
    transp_w<<<dim3(8, 8),  256, 0, stream>>>(Wv, WvT, 512, 512);
    cvt_bf16<<<6144, 256, 0, stream>>>(Wi, WiB, 2L * 1536 * 512);
    cvt_bf16<<<6144, 256, 0, stream>>>(Wh, WhB, 2L * 1536 * 512);
    pe_kernel<<<512, 256, 0, stream>>>(pe);

    // phase 1
    for (int g = 0; g < 8; g++) {
        embed_kernel<<<4096, 256, 0, stream>>>(cate, cont, emb, Wc, bc, xc, g * 4096);
        gemm_nt<<<dim3(4, 32, 1), 256, 0, stream>>>(
            xc, WcombT, xbf + (long)g * 4096 * 512, 1024, 1024, 1024, 512,
            0, 0, 0, bcomb, pe, 1.f, 1);
    }

    // phase 2 (QKV fused: one N=1536 GEMM per group)
    for (int g = 0; g < 8; g++) {
        const u16* xg = xbf + (long)g * 8 * 512 * 512;
        gemm_nt<<<dim3(12, 32, 1), 256, 0, stream>>>(xg, WqT, QKV, 512,
                                                     512, 512, 1536,
                                                     0, 0, 0, nullptr, nullptr, 1.f, 1);
        // Vt[b][d][s] from V (QKV cols 1024..1535, ld 1536)
        transp_b<<<dim3(8, 8, 8), 256, 0, stream>>>(QKV + 1024, Vt, 512, 512, 1536,
                                                    (long)512 * 1536, 262144, 512);
        // S[b] = Q[b] @ K[b]^T / sqrt(A)
        gemm_nt<<<dim3(4, 4, 8), 256, 0, stream>>>(QKV, QKV + 512, Sg, 512,
                                                   1536, 1536, 512,
                                                   (long)512 * 1536, (long)512 * 1536, 262144,
                                                   nullptr, nullptr,
                                                   0.04419417382415922f, 0);
        softmax_q<<<dim3(8, 8), 64, 0, stream>>>(Sg, Pg);
        // zT[b] = Vt[b] @ P[b]^T
        gemm_nt<<<dim3(4, 4, 8), 256, 0, stream>>>(Vt, Pg, zT, 512, 512, 512, 512,
                                                   262144, 262144, 262144, nullptr, nullptr,
                                                   1.f, 1);
        transp_b<<<dim3(8, 8, 8), 256, 0, stream>>>(zT, zp + (long)g * 8 * 512,
                                                    512, 512, 512, 262144, 512, 32768);
    }

    // phase 3: layer-fused pipelined GRU, 4 segment launches
    zero_kernel<<<513, 256, 0, stream>>>((float*)hx, 131328);
    for (int seg = 0; seg < 4; seg++) {
        gemm_nt<<<dim3(12, 64, 1), 256, 0, stream>>>(
            zp + (long)seg * 128 * 64 * 512, WiB, gi, 512, 512, 512, 1536,
            0, 0, 0, bi, nullptr, 1.f, 0);
        const float* giP = gi;
        const u16* wh0 = WhB;
        const u16* wh1 = WhB + 786432;
        const u16* wi1 = WiB + 786432;
        const float* bh0p = bh;
        const float* bh1p = bh + 1536;
        const float* bi1p = bi + 1536;
        u16* h1P = h1bf;
        u16* h2P = h2bf;
        u64* hxP = hx;
        int s0v = seg * 128;
        void* args[] = { (void*)&giP, (void*)&wh0, (void*)&wh1, (void*)&wi1,
                         (void*)&bh0p, (void*)&bh1p, (void*)&bi1p,
                         (void*)&h1P, (void*)&h2P, (void*)&hxP, (void*)&s0v };
        hipLaunchCooperativeKernel((void*)gru_fused, dim3(256), dim3(512),
                                   args, 0, stream);
    }

    final_kernel<<<8192, 256, 0, stream>>>(h2bf, Wf, bfin, out);
}

// Round 11
// 5402.166 us; speedup vs baseline: 1.3435x; 1.3435x over previous
//
#include <hip/hip_runtime.h>
#include <hip/hip_bf16.h>
#include <math.h>

typedef unsigned short u16;
typedef unsigned int   u32;
typedef unsigned long long u64;
typedef __attribute__((ext_vector_type(8))) short short8;
typedef __attribute__((ext_vector_type(4))) float float4v;

#define BB 64
#define SS 512

// bf16 helpers (RNE)
__device__ __forceinline__ u16 f2b(float f) {
    u32 x = __float_as_uint(f);
    u32 r = (x + 0x7fffu + ((x >> 16) & 1u)) >> 16;
    return (u16)r;
}
__device__ __forceinline__ float b2f(u32 lo16) { return __uint_as_float(lo16 << 16); }
__device__ __forceinline__ float b2fh(u32 v)   { return __uint_as_float(v & 0xffff0000u); }

// ---------------------------------------------------------------------------
__global__ __launch_bounds__(256) void zero_kernel(float* __restrict__ p, int n) {
    int i = blockIdx.x * 256 + threadIdx.x;
    if (i < n) p[i] = 0.f;
}

// ---------------------------------------------------------------------------
__global__ __launch_bounds__(256) void pe_kernel(float* __restrict__ pe) {
    int s = blockIdx.x, j = threadIdx.x;
    float ang = (float)s * powf(10000.0f, -(2.0f * (float)j) / 512.0f);
    pe[s * 512 + 2 * j]     = sinf(ang);
    pe[s * 512 + 2 * j + 1] = cosf(ang);
}

// ---------------------------------------------------------------------------
// fp32 [R][C] -> bf16 [C][R]
// ---------------------------------------------------------------------------
__global__ __launch_bounds__(256) void transp_w(const float* __restrict__ in,
                                                u16* __restrict__ out, int R, int C) {
    __shared__ float t[64][65];
    int r0 = blockIdx.x * 64, c0 = blockIdx.y * 64;
    int tid = threadIdx.x;
    int lr = tid >> 4, lc4 = (tid & 15) * 4;
#pragma unroll
    for (int i = 0; i < 4; i++) {
        int r = lr + i * 16;
        float4 v = *(const float4*)(in + (long)(r0 + r) * C + c0 + lc4);
        t[r][lc4] = v.x; t[r][lc4 + 1] = v.y; t[r][lc4 + 2] = v.z; t[r][lc4 + 3] = v.w;
    }
    __syncthreads();
#pragma unroll
    for (int i = 0; i < 4; i++) {
        int c = lr + i * 16;
        u32 lo = (u32)f2b(t[lc4][c])     | ((u32)f2b(t[lc4 + 1][c]) << 16);
        u32 hi = (u32)f2b(t[lc4 + 2][c]) | ((u32)f2b(t[lc4 + 3][c]) << 16);
        uint2 pk; pk.x = lo; pk.y = hi;
        *(uint2*)(out + (long)(c0 + c) * R + r0 + lc4) = pk;
    }
}

// ---------------------------------------------------------------------------
__global__ __launch_bounds__(256) void cvt_bf16(const float* __restrict__ in,
                                                u16* __restrict__ out, long n) {
    long i = (long)blockIdx.x * 256 + threadIdx.x;
    if (i < n) out[i] = f2b(in[i]);
}

// ---------------------------------------------------------------------------
// bf16 [nb][R][C(ldin)] -> out[b][c][r] with element strides
// ---------------------------------------------------------------------------
__global__ __launch_bounds__(256) void transp_b(const u16* __restrict__ in,
                                                u16* __restrict__ out,
                                                int R, int C, int ldin,
                                                long sbin, long sb, long sc) {
    __shared__ u32 t[64][65];
    int bz = blockIdx.z;
    in += (long)bz * sbin;
    int r0 = blockIdx.x * 64, c0 = blockIdx.y * 64;
    int tid = threadIdx.x;
    int lr = tid >> 4, lc4 = (tid & 15) * 4;
#pragma unroll
    for (int i = 0; i < 4; i++) {
        int r = lr + i * 16;
        uint2 v = *(const uint2*)(in + (long)(r0 + r) * ldin + c0 + lc4);
        t[r][lc4] = v.x & 0xffffu; t[r][lc4 + 1] = v.x >> 16;
        t[r][lc4 + 2] = v.y & 0xffffu; t[r][lc4 + 3] = v.y >> 16;
    }
    __syncthreads();
#pragma unroll
    for (int i = 0; i < 4; i++) {
        int c = lr + i * 16;
        uint2 pk;
        pk.x = t[lc4][c] | (t[lc4 + 1][c] << 16);
        pk.y = t[lc4 + 2][c] | (t[lc4 + 3][c] << 16);
        *(uint2*)(out + (long)bz * sb + (long)(c0 + c) * sc + r0 + lc4) = pk;
    }
}

// ---------------------------------------------------------------------------
__global__ __launch_bounds__(256) void embed_kernel(
    const int* __restrict__ cate, const float* __restrict__ cont,
    const float* __restrict__ emb, const float* __restrict__ Wc,
    const float* __restrict__ bc, u16* __restrict__ xc, int gbase)
{
    long bs = (long)gbase + blockIdx.x;
    long r  = blockIdx.x;
    __shared__ float cf[6];
    if (threadIdx.x < 6) cf[threadIdx.x] = cont[bs * 6 + threadIdx.x];
    __syncthreads();
    for (int h = threadIdx.x; h < 1024; h += 256) {
        float v;
        if (h < 512) {
            int c = h >> 7, e = h & 127;
            int idx = cate[bs * 4 + c];
            v = emb[((long)c * 1000 + idx) * 128 + e];
        } else {
            int hh = h - 512;
            v = bc[hh];
#pragma unroll
            for (int f = 0; f < 6; f++) v += cf[f] * Wc[f * 512 + hh];
        }
        xc[r * 1024 + h] = f2b(v);
    }
}

// ---------------------------------------------------------------------------
// bf16 MFMA NT GEMM (validated: absmax 0.0)
// ---------------------------------------------------------------------------
__global__ __launch_bounds__(256) void gemm_nt(
    const u16* __restrict__ A, const u16* __restrict__ B, void* __restrict__ Cv,
    int K, int lda, int ldb, int ldc,
    long sA, long sB, long sC,
    const float* __restrict__ bias, const float* __restrict__ pe,
    float alpha, int outBf16)
{
    __shared__ u16 As[128][40];
    __shared__ u16 Bs[128][40];

    A += (long)blockIdx.z * sA;
    B += (long)blockIdx.z * sB;
    int m0 = blockIdx.y * 128, n0 = blockIdx.x * 128;
    int tid = threadIdx.x;
    int lane = tid & 63, wid = tid >> 6;
    int wm = (wid >> 1) * 64, wn = (wid & 1) * 64;
    int mrow = lane & 15, q8 = (lane >> 4) * 8;

    float4v acc[4][4];
#pragma unroll
    for (int i = 0; i < 4; i++)
#pragma unroll
        for (int j = 0; j < 4; j++) { float4v z = {0.f, 0.f, 0.f, 0.f}; acc[i][j] = z; }

    for (int k0 = 0; k0 < K; k0 += 32) {
        {
            int r = tid >> 2, sg = tid & 3;
            *(short8*)&As[r][sg * 8] = *(const short8*)(A + (long)(m0 + r) * lda + k0 + sg * 8);
            *(short8*)&Bs[r][sg * 8] = *(const short8*)(B + (long)(n0 + r) * ldb + k0 + sg * 8);
            r = (tid + 256) >> 2;
            *(short8*)&As[r][sg * 8] = *(const short8*)(A + (long)(m0 + r) * lda + k0 + sg * 8);
            *(short8*)&Bs[r][sg * 8] = *(const short8*)(B + (long)(n0 + r) * ldb + k0 + sg * 8);
        }
        __syncthreads();
        short8 af[4], bfr[4];
#pragma unroll
        for (int t = 0; t < 4; t++) {
            af[t]  = *(const short8*)&As[wm + t * 16 + mrow][q8];
            bfr[t] = *(const short8*)&Bs[wn + t * 16 + mrow][q8];
        }
#pragma unroll
        for (int i = 0; i < 4; i++)
#pragma unroll
            for (int j = 0; j < 4; j++)
                acc[i][j] = __builtin_amdgcn_mfma_f32_16x16x32_bf16(af[i], bfr[j], acc[i][j], 0, 0, 0);
        __syncthreads();
    }

    int col = lane & 15, quad = lane >> 4;
    u16*  Cb = (u16*)Cv  + (outBf16 ? (long)blockIdx.z * sC : 0);
    float* Cf = (float*)Cv + (outBf16 ? 0 : (long)blockIdx.z * sC);
#pragma unroll
    for (int i = 0; i < 4; i++)
#pragma unroll
        for (int j = 0; j < 4; j++) {
#pragma unroll
            for (int rr = 0; rr < 4; rr++) {
                int gm = m0 + wm + i * 16 + quad * 4 + rr;
                int gn = n0 + wn + j * 16 + col;
                float v = acc[i][j][rr] * alpha;
                if (bias) v += bias[gn];
                if (pe)   v += pe[(long)(gm & 511) * 512 + gn];
                if (outBf16) Cb[(long)gm * ldc + gn] = f2b(v);
                else         Cf[(long)gm * ldc + gn] = v;
            }
        }
}

// ---------------------------------------------------------------------------
// Softmax over QUERY axis fp32 -> bf16
// ---------------------------------------------------------------------------
__global__ __launch_bounds__(64) void softmax_q(const float* __restrict__ S,
                                                u16* __restrict__ P) {
    int b = blockIdx.x;
    int k = blockIdx.y * 64 + threadIdx.x;
    const float* p = S + (long)b * 262144 + k;
    u16* o = P + (long)b * 262144 + k;
    float m = -1e30f;
    for (int q = 0; q < 512; q++) m = fmaxf(m, p[(long)q * 512]);
    float sum = 0.f;
    for (int q = 0; q < 512; q++) sum += expf(p[(long)q * 512] - m);
    float inv = 1.f / sum;
    for (int q = 0; q < 512; q++) o[(long)q * 512] = f2b(expf(p[(long)q * 512] - m) * inv);
}

// ---------------------------------------------------------------------------
// R11 GRU = R8 VERBATIM (validated absmax 0.0, 395 us/dispatch). 128 blocks
// = 8 XCD-confined batch-groups(8 batches) x 16 unit-slices(32 units);
// recurrent matvec = MFMA M=8 x N=96 x K=512 with Wh B-fragments preloaded
// ONCE into registers (R8: LDS-read path was the barrier A->B critical
// cost); h exchange = relaxed tag+spin u64 ring, batched 8-load sweeps,
// parity double buffer, 2-barrier loop. R10's fused variant NaN'd
// (unexplained after full audit) -> reverted per rigor.md.
// hx: u64[2 parity][8 bg][2048 slot], slot = pr*8 + b.
// ---------------------------------------------------------------------------
__global__ __launch_bounds__(256, 1) void gru_mfma(
    const float* __restrict__ gi,     // [128][64][1536] fp32 (includes bi)
    const u16*  __restrict__ WhB,     // [1536][512] bf16 (this layer)
    const float* __restrict__ bh_l,   // [1536]
    u16* __restrict__ seq_out,        // [512*64][512] bf16 (this layer)
    u64* __restrict__ hx,             // [2][8][2048] u64
    int s0, int layer)
{
    __shared__ u16 hlds[16 * 512];    // 16384 B  A-matrix h[b][k] bf16 (rows 8-15 zero)
    __shared__ float pre[3 * 16 * 34];// 6528 B   pre-activations [gate][b][u] (pad 34)
    __shared__ float hprev[8 * 32];   // 1024 B   own slice h fp32

    int blk = blockIdx.x;
    int bg  = blk & 7;                // batch group (8 batches) == XCD (round-robin)
    int us  = blk >> 3;               // unit slice 0..15 (32 units)
    int tid = threadIdx.x;
    int lane = tid & 63, wid = tid >> 6;

    // finalize mapping: thread (tid<128) = (batch fb 0..7, unit-pair up 0..15)
    int fb = (tid >> 4) & 7, up = tid & 15;
    int u0 = up << 1;
    int ug = (us << 5) + u0;          // global unit of u0
    float2 bhr = *(const float2*)(bh_l + ug);
    float2 bhz = *(const float2*)(bh_l + 512 + ug);
    float2 bhn = *(const float2*)(bh_l + 1024 + ug);

    // MFMA wave assignment: wid 0:{t0,t1} 1:{t2,t3} 2:{t4} 3:{t5}
    int t0 = (wid < 2) ? (wid << 1) : (wid + 2);
    int nt2 = (wid < 2);
    int bq = lane & 15, kq = (lane >> 4) << 3;
    char* hbase = (char*)hlds + (bq << 10);
    int swz = (bq & 7) << 4;

    // ---- preload B fragments into registers (constant across all steps).
    //      Element-identical to the old wlds path: lane holds B row
    //      r = t*16 + (lane&15), k = ks*32 + (lane>>4)*8 .. +8.
    short8 br0[16], br1[16];
    {
        int r_0 = (t0 << 4) + bq;
        long grow0 = (long)((r_0 >> 5) << 9) + (us << 5) + (r_0 & 31);
        const u16* wp0 = WhB + grow0 * 512 + kq;
#pragma unroll
        for (int ks = 0; ks < 16; ks++) br0[ks] = *(const short8*)(wp0 + ks * 32);
        if (nt2) {
            int r_1 = r_0 + 16;
            long grow1 = (long)((r_1 >> 5) << 9) + (us << 5) + (r_1 & 31);
            const u16* wp1 = WhB + grow1 * 512 + kq;
#pragma unroll
            for (int ks = 0; ks < 16; ks++) br1[ks] = *(const short8*)(wp1 + ks * 32);
        } else {
#pragma unroll
            for (int ks = 0; ks < 16; ks++) br1[ks] = br0[ks];
        }
    }

    for (int sl = 0; sl < 128; sl++) {
        int s = s0 + sl;

        // ---- gi prefetch (waves 0-1 only; independent of h exchange) ----
        float2 gir = {0.f, 0.f}, giz = {0.f, 0.f}, gin = {0.f, 0.f};
        if (tid < 128) {
            const float* g = gi + ((long)sl * 64 + (bg << 3) + fb) * 1536 + ug;
            gir = *(const float2*)g;
            giz = *(const float2*)(g + 512);
            gin = *(const float2*)(g + 1024);
        }

        // ---- gather h (or zero-init at layer start) ----
        if (s == 0) {
            u32* hz = (u32*)hlds;
            for (int i = tid; i < 4096; i += 256) hz[i] = 0;
        } else {
            u32 exp_tag = (u32)(layer * 512 + s);
            const u64* src = hx + ((long)(exp_tag & 1) << 14) + ((long)bg << 11) + tid;
            u32 need = 0xffu;
            int guard = 0;
            while (need) {
                // batch-issue all 8 loads (same-XCD L2 hits: cheap sweeps)
                u64 v[8];
#pragma unroll
                for (int j = 0; j < 8; j++)
                    v[j] = __hip_atomic_load(src + (j << 8), __ATOMIC_RELAXED, __HIP_MEMORY_SCOPE_AGENT);
#pragma unroll
                for (int j = 0; j < 8; j++) {
                    if ((need & (1u << j)) && (u32)(v[j] >> 32) == exp_tag) {
                        int i = tid + (j << 8);
                        int b = i & 7, pr = i >> 3;
                        *(u32*)((char*)hlds + ((b << 10) + ((pr << 2) ^ (b << 4)))) = (u32)v[j];
                        need &= ~(1u << j);
                    }
                }
                if (need) {
                    __builtin_amdgcn_s_sleep(1);
                    if (++guard > (1 << 12)) break;   // safety: never fires in correct runs
                }
            }
        }
        __syncthreads();   // barrier A: hlds complete

        // ---- segment start: restore own-slice fp32 h from gathered bf16 ----
        if (sl == 0 && tid < 128) {
            int pr = (us << 4) + up;
            u32 pk = *(u32*)((char*)hlds + ((fb << 10) + ((pr << 2) ^ (fb << 4))));
            hprev[(fb << 5) + u0]     = b2f(pk & 0xffffu);
            hprev[(fb << 5) + u0 + 1] = b2fh(pk);
        }

        // ---- MFMA: pre[16 b][96 gcol] = h[16][512] @ W[96][512]^T
        //      (B from registers; only 16 A ds_reads per wave) ----
        {
            float4v acc0 = {0.f, 0.f, 0.f, 0.f}, acc1 = {0.f, 0.f, 0.f, 0.f};
#pragma unroll
            for (int ks = 0; ks < 16; ks++) {
                int k2 = ((ks << 5) + kq) << 1;           // byte offset of k
                short8 a = *(const short8*)(hbase + (k2 ^ swz));
                acc0 = __builtin_amdgcn_mfma_f32_16x16x32_bf16(a, br0[ks], acc0, 0, 0, 0);
                if (nt2)
                    acc1 = __builtin_amdgcn_mfma_f32_16x16x32_bf16(a, br1[ks], acc1, 0, 0, 0);
            }
            int gq = lane >> 4;
            int g0 = t0 >> 1;
            int uu0 = ((t0 << 4) + (lane & 15)) & 31;
#pragma unroll
            for (int rr = 0; rr < 4; rr++) {
                int b = (gq << 2) + rr;
                pre[(g0 * 16 + b) * 34 + uu0] = acc0[rr];
                if (nt2) {
                    int t1 = t0 + 1;
                    int uu1 = ((t1 << 4) + (lane & 15)) & 31;
                    pre[((t1 >> 1) * 16 + b) * 34 + uu1] = acc1[rr];
                }
            }
        }
        __syncthreads();   // barrier B: pre complete; hlds reads done

        // ---- finalize: waves 0-1, 128 threads x 2 units (no barrier
        //      after; store drains overlap the next gather's spin) ----
        if (tid < 128) {
            float2 sr = *(const float2*)&pre[(0 * 16 + fb) * 34 + u0];
            float2 sz = *(const float2*)&pre[(1 * 16 + fb) * 34 + u0];
            float2 sn = *(const float2*)&pre[(2 * 16 + fb) * 34 + u0];
            float r0v = 1.f / (1.f + expf(-(gir.x + sr.x + bhr.x)));
            float r1v = 1.f / (1.f + expf(-(gir.y + sr.y + bhr.y)));
            float z0v = 1.f / (1.f + expf(-(giz.x + sz.x + bhz.x)));
            float z1v = 1.f / (1.f + expf(-(giz.y + sz.y + bhz.y)));
            float n0v = tanhf(gin.x + r0v * (sn.x + bhn.x));
            float n1v = tanhf(gin.y + r1v * (sn.y + bhn.y));
            float hp0 = hprev[(fb << 5) + u0];
            float hp1 = hprev[(fb << 5) + u0 + 1];
            float hn0 = (1.f - z0v) * n0v + z0v * hp0;
            float hn1 = (1.f - z1v) * n1v + z1v * hp1;
            hprev[(fb << 5) + u0]     = hn0;
            hprev[(fb << 5) + u0 + 1] = hn1;
            u16 q0 = f2b(hn0), q1 = f2b(hn1);
            u32 pk = ((u32)q1 << 16) | (u32)q0;
            u32 wt = (u32)(layer * 512 + s + 1);
            u64 pv = ((u64)wt << 32) | (u64)pk;
            int slot = (((us << 4) + up) << 3) + fb;   // pr*8 + b
            u64* dst = hx + ((long)(wt & 1) << 14) + ((long)bg << 11) + slot;
            __hip_atomic_store(dst, pv, __ATOMIC_RELAXED, __HIP_MEMORY_SCOPE_AGENT);
            *(u32*)(seq_out + ((long)s * 64 + (bg << 3) + fb) * 512 + ug) = pk;
        }
        // no barrier: finalize(t) ∥ gather(t+1) touch disjoint LDS
    }
}

// ---------------------------------------------------------------------------
__global__ __launch_bounds__(256) void final_kernel(
    const u16* __restrict__ h2, const float* __restrict__ Wf,
    const float* __restrict__ bfin, float* __restrict__ out)
{
    int w = blockIdx.x * 4 + (threadIdx.x >> 6);
    int lane = threadIdx.x & 63;
    const u16* row = h2 + (long)w * 512;
    uint4 hv = *(const uint4*)(row + lane * 8);
    float4 w0 = *(const float4*)(Wf + lane * 8);
    float4 w1 = *(const float4*)(Wf + lane * 8 + 4);
    float sum = b2f(hv.x & 0xffffu) * w0.x + b2fh(hv.x) * w0.y
              + b2f(hv.y & 0xffffu) * w0.z + b2fh(hv.y) * w0.w
              + b2f(hv.z & 0xffffu) * w1.x + b2fh(hv.z) * w1.y
              + b2f(hv.w & 0xffffu) * w1.z + b2fh(hv.w) * w1.w;
#pragma unroll
    for (int off = 32; off > 0; off >>= 1) sum += __shfl_down(sum, off, 64);
    if (lane == 0) {
        int s = w >> 6, b = w & 63;
        out[(long)b * 512 + s] = 1.f / (1.f + expf(-(sum + bfin[0])));
    }
}

// ---------------------------------------------------------------------------
// Launcher — workspace ~169.4 MB. R11: phase 1 consolidated to 2 launches
// (full-size xc at ws+0, provably dead region during phase 1: zp is first
// written in phase 2, h1bf in phase 3). GRU = R8 verbatim.
// ---------------------------------------------------------------------------
extern "C" void kernel_launch(void* const* d_in, const int* in_sizes, int n_in,
                              void* d_out, int out_size, void* d_ws, size_t ws_size,
                              hipStream_t stream) {
    const int*   cate  = (const int*)  d_in[0];
    const float* cont  = (const float*)d_in[1];
    const float* emb   = (const float*)d_in[4];
    const float* Wc    = (const float*)d_in[5];
    const float* bc    = (const float*)d_in[6];
    const float* Wcomb = (const float*)d_in[7];
    const float* bcomb = (const float*)d_in[8];
    const float* Wq    = (const float*)d_in[9];
    const float* Wk    = (const float*)d_in[10];
    const float* Wv    = (const float*)d_in[11];
    const float* Wi    = (const float*)d_in[12];
    const float* Wh    = (const float*)d_in[13];
    const float* bi    = (const float*)d_in[14];
    const float* bh    = (const float*)d_in[15];
    const float* Wf    = (const float*)d_in[16];
    const float* bfin  = (const float*)d_in[17];
    float* out = (float*)d_out;
    char* ws = (char*)d_ws;

    u16*   xcF   = (u16*)(ws + 0);            // phase-1 only: [32768][1024] = 67 MB
    u16*   zp    = (u16*)(ws + 0);
    u16*   h2bf  = (u16*)(ws + 0);
    u16*   h1bf  = (u16*)(ws + 33554432);
    float* gi    = (float*)(ws + 67108864);   // 50.3 MB, aliases xbf
    u16*   xbf   = (u16*)(ws + 67108864);
    u16*   QKV   = (u16*)(ws + 117440512);    // [4096][1536] bf16 = 12.58 MB
    u16*   Vt    = (u16*)(ws + 130023424);
    float* Sg    = (float*)(ws + 134217728);  // phase-2 only
    u64*   hx    = (u64*)  (ws + 134217728);  // 256 KB, aliases dead Sg (phase 3)
    u16*   Pg    = (u16*)(ws + 142606336);
    u16*   zT    = (u16*)(ws + 146800640);
    u16*   WcombT= (u16*)(ws + 159383552);
    u16*   WqT   = (u16*)(ws + 160432128);    // contiguous: WqT|WkT|WvT = [1536][512]
    u16*   WkT   = (u16*)(ws + 160956416);
    u16*   WvT   = (u16*)(ws + 161480704);
    u16*   WiB   = (u16*)(ws + 162004992);
    float* pe    = (float*)(ws + 165150720);
    u16*   WhB   = (u16*)(ws + 166199296);    // [2][1536][512] bf16 = 3.15 MB

    transp_w<<<dim3(16, 8), 256, 0, stream>>>(Wcomb, WcombT, 1024, 512);
    transp_w<<<dim3(8, 8),  256, 0, stream>>>(Wq, WqT, 512, 512);
    transp_w<<<dim3(8, 8),  256, 0, stream>>>(Wk, WkT, 512, 512);
    transp_w<<<dim3(8, 8),  256, 0, stream>>>(Wv, WvT, 512, 512);
    cvt_bf16<<<6144, 256, 0, stream>>>(Wi, WiB, 2L * 1536 * 512);
    cvt_bf16<<<6144, 256, 0, stream>>>(Wh, WhB, 2L * 1536 * 512);
    pe_kernel<<<512, 256, 0, stream>>>(pe);

    // phase 1 — consolidated: ONE embed over all 32768 rows + ONE GEMM
    embed_kernel<<<32768, 256, 0, stream>>>(cate, cont, emb, Wc, bc, xcF, 0);
    gemm_nt<<<dim3(4, 256, 1), 256, 0, stream>>>(
        xcF, WcombT, xbf, 1024, 1024, 1024, 512,
        0, 0, 0, bcomb, pe, 1.f, 1);

    // phase 2 (QKV fused: one N=1536 GEMM per group)
    for (int g = 0; g < 8; g++) {
        const u16* xg = xbf + (long)g * 8 * 512 * 512;
        gemm_nt<<<dim3(12, 32, 1), 256, 0, stream>>>(xg, WqT, QKV, 512,
                                                     512, 512, 1536,
                                                     0, 0, 0, nullptr, nullptr, 1.f, 1);
        // Vt[b][d][s] from V (QKV cols 1024..1535, ld 1536)
        transp_b<<<dim3(8, 8, 8), 256, 0, stream>>>(QKV + 1024, Vt, 512, 512, 1536,
                                                    (long)512 * 1536, 262144, 512);
        // S[b] = Q[b] @ K[b]^T / sqrt(A)
        gemm_nt<<<dim3(4, 4, 8), 256, 0, stream>>>(QKV, QKV + 512, Sg, 512,
                                                   1536, 1536, 512,
                                                   (long)512 * 1536, (long)512 * 1536, 262144,
                                                   nullptr, nullptr,
                                                   0.04419417382415922f, 0);
        softmax_q<<<dim3(8, 8), 64, 0, stream>>>(Sg, Pg);
        // zT[b] = Vt[b] @ P[b]^T
        gemm_nt<<<dim3(4, 4, 8), 256, 0, stream>>>(Vt, Pg, zT, 512, 512, 512, 512,
                                                   262144, 262144, 262144, nullptr, nullptr,
                                                   1.f, 1);
        transp_b<<<dim3(8, 8, 8), 256, 0, stream>>>(zT, zp + (long)g * 8 * 512,
                                                    512, 512, 512, 262144, 512, 32768);
    }

    // phase 3: GRU — MFMA, 128 blocks (8 XCD-confined bg x 16 unit-slices)
    zero_kernel<<<256, 256, 0, stream>>>((float*)hx, 65536);
    for (int l = 0; l < 2; l++) {
        const u16* Aseq = (l == 0) ? zp : h1bf;
        u16* seqOut = (l == 0) ? h1bf : h2bf;
        const u16* WiL = WiB + (long)l * 1536 * 512;
        const u16* WhL = WhB + (long)l * 1536 * 512;
        const float* biL = bi + (long)l * 1536;
        const float* bhL = bh + (long)l * 1536;
        for (int seg = 0; seg < 4; seg++) {
            gemm_nt<<<dim3(12, 64, 1), 256, 0, stream>>>(
                Aseq + (long)seg * 128 * 64 * 512, WiL, gi, 512, 512, 512, 1536,
                0, 0, 0, biL, nullptr, 1.f, 0);
            const float* giP = gi;
            u16* soP = seqOut;
            int s0v = seg * 128;
            int lv = l;
            void* args[] = { (void*)&giP, (void*)&WhL, (void*)&bhL, (void*)&soP,
                             (void*)&hx, (void*)&s0v, (void*)&lv };
            hipLaunchCooperativeKernel((void*)gru_mfma, dim3(128), dim3(256),
                                       args, 0, stream);
        }
    }

    final_kernel<<<8192, 256, 0, stream>>>(h2bf, Wf, bfin, out);
}

// Round 13
// 4624.999 us; speedup vs baseline: 1.5693x; 1.1680x over previous
//
#include <hip/hip_runtime.h>
#include <hip/hip_bf16.h>
#include <math.h>

typedef unsigned short u16;
typedef unsigned int   u32;
typedef unsigned long long u64;
typedef __attribute__((ext_vector_type(8))) short short8;
typedef __attribute__((ext_vector_type(4))) float float4v;

#define BB 64
#define SS 512

// bf16 helpers (RNE)
__device__ __forceinline__ u16 f2b(float f) {
    u32 x = __float_as_uint(f);
    u32 r = (x + 0x7fffu + ((x >> 16) & 1u)) >> 16;
    return (u16)r;
}
__device__ __forceinline__ float b2f(u32 lo16) { return __uint_as_float(lo16 << 16); }
__device__ __forceinline__ float b2fh(u32 v)   { return __uint_as_float(v & 0xffff0000u); }

// ---------------------------------------------------------------------------
__global__ __launch_bounds__(256) void zero_kernel(float* __restrict__ p, int n) {
    int i = blockIdx.x * 256 + threadIdx.x;
    if (i < n) p[i] = 0.f;
}

// ---------------------------------------------------------------------------
__global__ __launch_bounds__(256) void pe_kernel(float* __restrict__ pe) {
    int s = blockIdx.x, j = threadIdx.x;
    float ang = (float)s * powf(10000.0f, -(2.0f * (float)j) / 512.0f);
    pe[s * 512 + 2 * j]     = sinf(ang);
    pe[s * 512 + 2 * j + 1] = cosf(ang);
}

// ---------------------------------------------------------------------------
// fp32 [R][C] -> bf16 [C][R]
// ---------------------------------------------------------------------------
__global__ __launch_bounds__(256) void transp_w(const float* __restrict__ in,
                                                u16* __restrict__ out, int R, int C) {
    __shared__ float t[64][65];
    int r0 = blockIdx.x * 64, c0 = blockIdx.y * 64;
    int tid = threadIdx.x;
    int lr = tid >> 4, lc4 = (tid & 15) * 4;
#pragma unroll
    for (int i = 0; i < 4; i++) {
        int r = lr + i * 16;
        float4 v = *(const float4*)(in + (long)(r0 + r) * C + c0 + lc4);
        t[r][lc4] = v.x; t[r][lc4 + 1] = v.y; t[r][lc4 + 2] = v.z; t[r][lc4 + 3] = v.w;
    }
    __syncthreads();
#pragma unroll
    for (int i = 0; i < 4; i++) {
        int c = lr + i * 16;
        u32 lo = (u32)f2b(t[lc4][c])     | ((u32)f2b(t[lc4 + 1][c]) << 16);
        u32 hi = (u32)f2b(t[lc4 + 2][c]) | ((u32)f2b(t[lc4 + 3][c]) << 16);
        uint2 pk; pk.x = lo; pk.y = hi;
        *(uint2*)(out + (long)(c0 + c) * R + r0 + lc4) = pk;
    }
}

// ---------------------------------------------------------------------------
__global__ __launch_bounds__(256) void cvt_bf16(const float* __restrict__ in,
                                                u16* __restrict__ out, long n) {
    long i = (long)blockIdx.x * 256 + threadIdx.x;
    if (i < n) out[i] = f2b(in[i]);
}

// ---------------------------------------------------------------------------
// bf16 [nb][R][C(ldin)] -> out[b][c][r] with element strides
// ---------------------------------------------------------------------------
__global__ __launch_bounds__(256) void transp_b(const u16* __restrict__ in,
                                                u16* __restrict__ out,
                                                int R, int C, int ldin,
                                                long sbin, long sb, long sc) {
    __shared__ u32 t[64][65];
    int bz = blockIdx.z;
    in += (long)bz * sbin;
    int r0 = blockIdx.x * 64, c0 = blockIdx.y * 64;
    int tid = threadIdx.x;
    int lr = tid >> 4, lc4 = (tid & 15) * 4;
#pragma unroll
    for (int i = 0; i < 4; i++) {
        int r = lr + i * 16;
        uint2 v = *(const uint2*)(in + (long)(r0 + r) * ldin + c0 + lc4);
        t[r][lc4] = v.x & 0xffffu; t[r][lc4 + 1] = v.x >> 16;
        t[r][lc4 + 2] = v.y & 0xffffu; t[r][lc4 + 3] = v.y >> 16;
    }
    __syncthreads();
#pragma unroll
    for (int i = 0; i < 4; i++) {
        int c = lr + i * 16;
        uint2 pk;
        pk.x = t[lc4][c] | (t[lc4 + 1][c] << 16);
        pk.y = t[lc4 + 2][c] | (t[lc4 + 3][c] << 16);
        *(uint2*)(out + (long)bz * sb + (long)(c0 + c) * sc + r0 + lc4) = pk;
    }
}

// ---------------------------------------------------------------------------
__global__ __launch_bounds__(256) void embed_kernel(
    const int* __restrict__ cate, const float* __restrict__ cont,
    const float* __restrict__ emb, const float* __restrict__ Wc,
    const float* __restrict__ bc, u16* __restrict__ xc, int gbase)
{
    long bs = (long)gbase + blockIdx.x;
    long r  = blockIdx.x;
    __shared__ float cf[6];
    if (threadIdx.x < 6) cf[threadIdx.x] = cont[bs * 6 + threadIdx.x];
    __syncthreads();
    for (int h = threadIdx.x; h < 1024; h += 256) {
        float v;
        if (h < 512) {
            int c = h >> 7, e = h & 127;
            int idx = cate[bs * 4 + c];
            v = emb[((long)c * 1000 + idx) * 128 + e];
        } else {
            int hh = h - 512;
            v = bc[hh];
#pragma unroll
            for (int f = 0; f < 6; f++) v += cf[f] * Wc[f * 512 + hh];
        }
        xc[r * 1024 + h] = f2b(v);
    }
}

// ---------------------------------------------------------------------------
// bf16 MFMA NT GEMM (validated: absmax 0.0)
// ---------------------------------------------------------------------------
__global__ __launch_bounds__(256) void gemm_nt(
    const u16* __restrict__ A, const u16* __restrict__ B, void* __restrict__ Cv,
    int K, int lda, int ldb, int ldc,
    long sA, long sB, long sC,
    const float* __restrict__ bias, const float* __restrict__ pe,
    float alpha, int outBf16)
{
    __shared__ u16 As[128][40];
    __shared__ u16 Bs[128][40];

    A += (long)blockIdx.z * sA;
    B += (long)blockIdx.z * sB;
    int m0 = blockIdx.y * 128, n0 = blockIdx.x * 128;
    int tid = threadIdx.x;
    int lane = tid & 63, wid = tid >> 6;
    int wm = (wid >> 1) * 64, wn = (wid & 1) * 64;
    int mrow = lane & 15, q8 = (lane >> 4) * 8;

    float4v acc[4][4];
#pragma unroll
    for (int i = 0; i < 4; i++)
#pragma unroll
        for (int j = 0; j < 4; j++) { float4v z = {0.f, 0.f, 0.f, 0.f}; acc[i][j] = z; }

    for (int k0 = 0; k0 < K; k0 += 32) {
        {
            int r = tid >> 2, sg = tid & 3;
            *(short8*)&As[r][sg * 8] = *(const short8*)(A + (long)(m0 + r) * lda + k0 + sg * 8);
            *(short8*)&Bs[r][sg * 8] = *(const short8*)(B + (long)(n0 + r) * ldb + k0 + sg * 8);
            r = (tid + 256) >> 2;
            *(short8*)&As[r][sg * 8] = *(const short8*)(A + (long)(m0 + r) * lda + k0 + sg * 8);
            *(short8*)&Bs[r][sg * 8] = *(const short8*)(B + (long)(n0 + r) * ldb + k0 + sg * 8);
        }
        __syncthreads();
        short8 af[4], bfr[4];
#pragma unroll
        for (int t = 0; t < 4; t++) {
            af[t]  = *(const short8*)&As[wm + t * 16 + mrow][q8];
            bfr[t] = *(const short8*)&Bs[wn + t * 16 + mrow][q8];
        }
#pragma unroll
        for (int i = 0; i < 4; i++)
#pragma unroll
            for (int j = 0; j < 4; j++)
                acc[i][j] = __builtin_amdgcn_mfma_f32_16x16x32_bf16(af[i], bfr[j], acc[i][j], 0, 0, 0);
        __syncthreads();
    }

    int col = lane & 15, quad = lane >> 4;
    u16*  Cb = (u16*)Cv  + (outBf16 ? (long)blockIdx.z * sC : 0);
    float* Cf = (float*)Cv + (outBf16 ? 0 : (long)blockIdx.z * sC);
#pragma unroll
    for (int i = 0; i < 4; i++)
#pragma unroll
        for (int j = 0; j < 4; j++) {
#pragma unroll
            for (int rr = 0; rr < 4; rr++) {
                int gm = m0 + wm + i * 16 + quad * 4 + rr;
                int gn = n0 + wn + j * 16 + col;
                float v = acc[i][j][rr] * alpha;
                if (bias) v += bias[gn];
                if (pe)   v += pe[(long)(gm & 511) * 512 + gn];
                if (outBf16) Cb[(long)gm * ldc + gn] = f2b(v);
                else         Cf[(long)gm * ldc + gn] = v;
            }
        }
}

// ---------------------------------------------------------------------------
// Softmax over QUERY axis fp32 -> bf16
// ---------------------------------------------------------------------------
__global__ __launch_bounds__(64) void softmax_q(const float* __restrict__ S,
                                                u16* __restrict__ P) {
    int b = blockIdx.x;
    int k = blockIdx.y * 64 + threadIdx.x;
    const float* p = S + (long)b * 262144 + k;
    u16* o = P + (long)b * 262144 + k;
    float m = -1e30f;
    for (int q = 0; q < 512; q++) m = fmaxf(m, p[(long)q * 512]);
    float sum = 0.f;
    for (int q = 0; q < 512; q++) sum += expf(p[(long)q * 512] - m);
    float inv = 1.f / sum;
    for (int q = 0; q < 512; q++) o[(long)q * 512] = f2b(expf(p[(long)q * 512] - m) * inv);
}

// ---------------------------------------------------------------------------
// R13 GRU = R8/R11 VERBATIM (validated absmax 0.0, 395 us/dispatch).
// 128 blocks = 8 XCD-confined batch-groups(8 batches) x 16 unit-slices(32
// units); recurrent matvec = MFMA M=8 x N=96 x K=512 with Wh B-fragments
// preloaded ONCE into registers; h exchange = relaxed tag+spin u64 ring,
// batched 8-load sweeps, parity double buffer, 2-barrier loop. Layer
// fusion abandoned after two unexplained failures (R10 NaN, R12 1.6e-2);
// prime suspect was wave-divergent __syncthreads in R12 — not re-rolled.
// hx: u64[2 parity][8 bg][2048 slot], slot = pr*8 + b.
// ---------------------------------------------------------------------------
__global__ __launch_bounds__(256, 1) void gru_mfma(
    const float* __restrict__ gi,     // [128][64][1536] fp32 (includes bi)
    const u16*  __restrict__ WhB,     // [1536][512] bf16 (this layer)
    const float* __restrict__ bh_l,   // [1536]
    u16* __restrict__ seq_out,        // [512*64][512] bf16 (this layer)
    u64* __restrict__ hx,             // [2][8][2048] u64
    int s0, int layer)
{
    __shared__ u16 hlds[16 * 512];    // 16384 B  A-matrix h[b][k] bf16 (rows 8-15 zero)
    __shared__ float pre[3 * 16 * 34];// 6528 B   pre-activations [gate][b][u] (pad 34)
    __shared__ float hprev[8 * 32];   // 1024 B   own slice h fp32

    int blk = blockIdx.x;
    int bg  = blk & 7;                // batch group (8 batches) == XCD (round-robin)
    int us  = blk >> 3;               // unit slice 0..15 (32 units)
    int tid = threadIdx.x;
    int lane = tid & 63, wid = tid >> 6;

    // finalize mapping: thread (tid<128) = (batch fb 0..7, unit-pair up 0..15)
    int fb = (tid >> 4) & 7, up = tid & 15;
    int u0 = up << 1;
    int ug = (us << 5) + u0;          // global unit of u0
    float2 bhr = *(const float2*)(bh_l + ug);
    float2 bhz = *(const float2*)(bh_l + 512 + ug);
    float2 bhn = *(const float2*)(bh_l + 1024 + ug);

    // MFMA wave assignment: wid 0:{t0,t1} 1:{t2,t3} 2:{t4} 3:{t5}
    int t0 = (wid < 2) ? (wid << 1) : (wid + 2);
    int nt2 = (wid < 2);
    int bq = lane & 15, kq = (lane >> 4) << 3;
    char* hbase = (char*)hlds + (bq << 10);
    int swz = (bq & 7) << 4;

    // ---- preload B fragments into registers (constant across all steps).
    short8 br0[16], br1[16];
    {
        int r_0 = (t0 << 4) + bq;
        long grow0 = (long)((r_0 >> 5) << 9) + (us << 5) + (r_0 & 31);
        const u16* wp0 = WhB + grow0 * 512 + kq;
#pragma unroll
        for (int ks = 0; ks < 16; ks++) br0[ks] = *(const short8*)(wp0 + ks * 32);
        if (nt2) {
            int r_1 = r_0 + 16;
            long grow1 = (long)((r_1 >> 5) << 9) + (us << 5) + (r_1 & 31);
            const u16* wp1 = WhB + grow1 * 512 + kq;
#pragma unroll
            for (int ks = 0; ks < 16; ks++) br1[ks] = *(const short8*)(wp1 + ks * 32);
        } else {
#pragma unroll
            for (int ks = 0; ks < 16; ks++) br1[ks] = br0[ks];
        }
    }

    for (int sl = 0; sl < 128; sl++) {
        int s = s0 + sl;

        // ---- gi prefetch (waves 0-1 only; independent of h exchange) ----
        float2 gir = {0.f, 0.f}, giz = {0.f, 0.f}, gin = {0.f, 0.f};
        if (tid < 128) {
            const float* g = gi + ((long)sl * 64 + (bg << 3) + fb) * 1536 + ug;
            gir = *(const float2*)g;
            giz = *(const float2*)(g + 512);
            gin = *(const float2*)(g + 1024);
        }

        // ---- gather h (or zero-init at layer start) ----
        if (s == 0) {
            u32* hz = (u32*)hlds;
            for (int i = tid; i < 4096; i += 256) hz[i] = 0;
        } else {
            u32 exp_tag = (u32)(layer * 512 + s);
            const u64* src = hx + ((long)(exp_tag & 1) << 14) + ((long)bg << 11) + tid;
            u32 need = 0xffu;
            int guard = 0;
            while (need) {
                // batch-issue all 8 loads (same-XCD L2 hits: cheap sweeps)
                u64 v[8];
#pragma unroll
                for (int j = 0; j < 8; j++)
                    v[j] = __hip_atomic_load(src + (j << 8), __ATOMIC_RELAXED, __HIP_MEMORY_SCOPE_AGENT);
#pragma unroll
                for (int j = 0; j < 8; j++) {
                    if ((need & (1u << j)) && (u32)(v[j] >> 32) == exp_tag) {
                        int i = tid + (j << 8);
                        int b = i & 7, pr = i >> 3;
                        *(u32*)((char*)hlds + ((b << 10) + ((pr << 2) ^ (b << 4)))) = (u32)v[j];
                        need &= ~(1u << j);
                    }
                }
                if (need) {
                    __builtin_amdgcn_s_sleep(1);
                    if (++guard > (1 << 12)) break;   // safety: never fires in correct runs
                }
            }
        }
        __syncthreads();   // barrier A: hlds complete

        // ---- segment start: restore own-slice fp32 h from gathered bf16 ----
        if (sl == 0 && tid < 128) {
            int pr = (us << 4) + up;
            u32 pk = *(u32*)((char*)hlds + ((fb << 10) + ((pr << 2) ^ (fb << 4))));
            hprev[(fb << 5) + u0]     = b2f(pk & 0xffffu);
            hprev[(fb << 5) + u0 + 1] = b2fh(pk);
        }

        // ---- MFMA: pre[16 b][96 gcol] = h[16][512] @ W[96][512]^T
        //      (B from registers; only 16 A ds_reads per wave) ----
        {
            float4v acc0 = {0.f, 0.f, 0.f, 0.f}, acc1 = {0.f, 0.f, 0.f, 0.f};
#pragma unroll
            for (int ks = 0; ks < 16; ks++) {
                int k2 = ((ks << 5) + kq) << 1;           // byte offset of k
                short8 a = *(const short8*)(hbase + (k2 ^ swz));
                acc0 = __builtin_amdgcn_mfma_f32_16x16x32_bf16(a, br0[ks], acc0, 0, 0, 0);
                if (nt2)
                    acc1 = __builtin_amdgcn_mfma_f32_16x16x32_bf16(a, br1[ks], acc1, 0, 0, 0);
            }
            int gq = lane >> 4;
            int g0 = t0 >> 1;
            int uu0 = ((t0 << 4) + (lane & 15)) & 31;
#pragma unroll
            for (int rr = 0; rr < 4; rr++) {
                int b = (gq << 2) + rr;
                pre[(g0 * 16 + b) * 34 + uu0] = acc0[rr];
                if (nt2) {
                    int t1 = t0 + 1;
                    int uu1 = ((t1 << 4) + (lane & 15)) & 31;
                    pre[((t1 >> 1) * 16 + b) * 34 + uu1] = acc1[rr];
                }
            }
        }
        __syncthreads();   // barrier B: pre complete; hlds reads done

        // ---- finalize: waves 0-1, 128 threads x 2 units (no barrier
        //      after; store drains overlap the next gather's spin) ----
        if (tid < 128) {
            float2 sr = *(const float2*)&pre[(0 * 16 + fb) * 34 + u0];
            float2 sz = *(const float2*)&pre[(1 * 16 + fb) * 34 + u0];
            float2 sn = *(const float2*)&pre[(2 * 16 + fb) * 34 + u0];
            float r0v = 1.f / (1.f + expf(-(gir.x + sr.x + bhr.x)));
            float r1v = 1.f / (1.f + expf(-(gir.y + sr.y + bhr.y)));
            float z0v = 1.f / (1.f + expf(-(giz.x + sz.x + bhz.x)));
            float z1v = 1.f / (1.f + expf(-(giz.y + sz.y + bhz.y)));
            float n0v = tanhf(gin.x + r0v * (sn.x + bhn.x));
            float n1v = tanhf(gin.y + r1v * (sn.y + bhn.y));
            float hp0 = hprev[(fb << 5) + u0];
            float hp1 = hprev[(fb << 5) + u0 + 1];
            float hn0 = (1.f - z0v) * n0v + z0v * hp0;
            float hn1 = (1.f - z1v) * n1v + z1v * hp1;
            hprev[(fb << 5) + u0]     = hn0;
            hprev[(fb << 5) + u0 + 1] = hn1;
            u16 q0 = f2b(hn0), q1 = f2b(hn1);
            u32 pk = ((u32)q1 << 16) | (u32)q0;
            u32 wt = (u32)(layer * 512 + s + 1);
            u64 pv = ((u64)wt << 32) | (u64)pk;
            int slot = (((us << 4) + up) << 3) + fb;   // pr*8 + b
            u64* dst = hx + ((long)(wt & 1) << 14) + ((long)bg << 11) + slot;
            __hip_atomic_store(dst, pv, __ATOMIC_RELAXED, __HIP_MEMORY_SCOPE_AGENT);
            *(u32*)(seq_out + ((long)s * 64 + (bg << 3) + fb) * 512 + ug) = pk;
        }
        // no barrier: finalize(t) ∥ gather(t+1) touch disjoint LDS
    }
}

// ---------------------------------------------------------------------------
__global__ __launch_bounds__(256) void final_kernel(
    const u16* __restrict__ h2, const float* __restrict__ Wf,
    const float* __restrict__ bfin, float* __restrict__ out)
{
    int w = blockIdx.x * 4 + (threadIdx.x >> 6);
    int lane = threadIdx.x & 63;
    const u16* row = h2 + (long)w * 512;
    uint4 hv = *(const uint4*)(row + lane * 8);
    float4 w0 = *(const float4*)(Wf + lane * 8);
    float4 w1 = *(const float4*)(Wf + lane * 8 + 4);
    float sum = b2f(hv.x & 0xffffu) * w0.x + b2fh(hv.x) * w0.y
              + b2f(hv.y & 0xffffu) * w0.z + b2fh(hv.y) * w0.w
              + b2f(hv.z & 0xffffu) * w1.x + b2fh(hv.z) * w1.y
              + b2f(hv.w & 0xffffu) * w1.z + b2fh(hv.w) * w1.w;
#pragma unroll
    for (int off = 32; off > 0; off >>= 1) sum += __shfl_down(sum, off, 64);
    if (lane == 0) {
        int s = w >> 6, b = w & 63;
        out[(long)b * 512 + s] = 1.f / (1.f + expf(-(sum + bfin[0])));
    }
}

// ---------------------------------------------------------------------------
// Launcher — workspace ~169.4 MB. R13: phase 2 consolidated to 4 super-
// groups of 16 batches (24 launches vs 48). Phase-2 buffers (all dead
// outside phase 2): QKV2 @100.66MB (25.2MB, overlaps gi's tail — gi live
// only in phase 3), Sg2 @125.8MB (16.8MB), Vt2 @142.6MB (8.4MB),
// Pg2/zT2 in the h1bf region (h1bf first written in phase 3).
// Phase-1 consolidation (R11) and R8-verbatim GRU kept.
// ---------------------------------------------------------------------------
extern "C" void kernel_launch(void* const* d_in, const int* in_sizes, int n_in,
                              void* d_out, int out_size, void* d_ws, size_t ws_size,
                              hipStream_t stream) {
    const int*   cate  = (const int*)  d_in[0];
    const float* cont  = (const float*)d_in[1];
    const float* emb   = (const float*)d_in[4];
    const float* Wc    = (const float*)d_in[5];
    const float* bc    = (const float*)d_in[6];
    const float* Wcomb = (const float*)d_in[7];
    const float* bcomb = (const float*)d_in[8];
    const float* Wq    = (const float*)d_in[9];
    const float* Wk    = (const float*)d_in[10];
    const float* Wv    = (const float*)d_in[11];
    const float* Wi    = (const float*)d_in[12];
    const float* Wh    = (const float*)d_in[13];
    const float* bi    = (const float*)d_in[14];
    const float* bh    = (const float*)d_in[15];
    const float* Wf    = (const float*)d_in[16];
    const float* bfin  = (const float*)d_in[17];
    float* out = (float*)d_out;
    char* ws = (char*)d_ws;

    u16*   xcF   = (u16*)(ws + 0);            // phase-1 only: [32768][1024] = 67 MB
    u16*   zp    = (u16*)(ws + 0);            // phase-2 out / phase-3 L0 in
    u16*   h2bf  = (u16*)(ws + 0);            // phase-3 L1 out (zp dead by then)
    u16*   h1bf  = (u16*)(ws + 33554432);     // phase-3 only
    u16*   Pg2   = (u16*)(ws + 33554432);     // phase-2 only (h1bf region)
    u16*   zT2   = (u16*)(ws + 41943040);     // phase-2 only (h1bf region)
    float* gi    = (float*)(ws + 67108864);   // phase-3, 50.3 MB (overlaps xbf+QKV2)
    u16*   xbf   = (u16*)(ws + 67108864);     // 33.5 MB
    u16*   QKV2  = (u16*)(ws + 100663296);    // phase-2: [8192][1536] bf16 = 25.2 MB
    float* Sg2   = (float*)(ws + 125829120);  // phase-2: [16][512][512] fp32 = 16.8 MB
    u64*   hx    = (u64*)  (ws + 134217728);  // phase-3: 256 KB (inside dead Sg2)
    u16*   Vt2   = (u16*)(ws + 142606336);    // phase-2: 8.4 MB
    u16*   WcombT= (u16*)(ws + 159383552);
    u16*   WqT   = (u16*)(ws + 160432128);    // contiguous: WqT|WkT|WvT = [1536][512]
    u16*   WkT   = (u16*)(ws + 160956416);
    u16*   WvT   = (u16*)(ws + 161480704);
    u16*   WiB   = (u16*)(ws + 162004992);
    float* pe    = (float*)(ws + 165150720);
    u16*   WhB   = (u16*)(ws + 166199296);    // [2][1536][512] bf16 = 3.15 MB

    transp_w<<<dim3(16, 8), 256, 0, stream>>>(Wcomb, WcombT, 1024, 512);
    transp_w<<<dim3(8, 8),  256, 0, stream>>>(Wq, WqT, 512, 512);
    transp_w<<<dim3(8, 8),  256, 0, stream>>>(Wk, WkT, 512, 512);
    transp_w<<<dim3(8, 8),  256, 0, stream>>>(Wv, WvT, 512, 512);
    cvt_bf16<<<6144, 256, 0, stream>>>(Wi, WiB, 2L * 1536 * 512);
    cvt_bf16<<<6144, 256, 0, stream>>>(Wh, WhB, 2L * 1536 * 512);
    pe_kernel<<<512, 256, 0, stream>>>(pe);

    // phase 1 — consolidated: ONE embed + ONE GEMM (R11)
    embed_kernel<<<32768, 256, 0, stream>>>(cate, cont, emb, Wc, bc, xcF, 0);
    gemm_nt<<<dim3(4, 256, 1), 256, 0, stream>>>(
        xcF, WcombT, xbf, 1024, 1024, 1024, 512,
        0, 0, 0, bcomb, pe, 1.f, 1);

    // phase 2 — 4 super-groups of 16 batches (6 launches each)
    for (int G = 0; G < 4; G++) {
        const u16* xg = xbf + (long)G * 16 * 512 * 512;
        // QKV for 16 batches: M=8192, N=1536
        gemm_nt<<<dim3(12, 64, 1), 256, 0, stream>>>(xg, WqT, QKV2, 512,
                                                     512, 512, 1536,
                                                     0, 0, 0, nullptr, nullptr, 1.f, 1);
        // Vt[b][d][s] from V (QKV2 cols 1024..1535, ld 1536)
        transp_b<<<dim3(8, 8, 16), 256, 0, stream>>>(QKV2 + 1024, Vt2, 512, 512, 1536,
                                                     (long)512 * 1536, 262144, 512);
        // S[b] = Q[b] @ K[b]^T / sqrt(A)
        gemm_nt<<<dim3(4, 4, 16), 256, 0, stream>>>(QKV2, QKV2 + 512, Sg2, 512,
                                                    1536, 1536, 512,
                                                    (long)512 * 1536, (long)512 * 1536, 262144,
                                                    nullptr, nullptr,
                                                    0.04419417382415922f, 0);
        softmax_q<<<dim3(16, 8), 64, 0, stream>>>(Sg2, Pg2);
        // zT[b] = Vt[b] @ P[b]^T
        gemm_nt<<<dim3(4, 4, 16), 256, 0, stream>>>(Vt2, Pg2, zT2, 512, 512, 512, 512,
                                                    262144, 262144, 262144, nullptr, nullptr,
                                                    1.f, 1);
        transp_b<<<dim3(8, 8, 16), 256, 0, stream>>>(zT2, zp + (long)G * 16 * 512,
                                                     512, 512, 512, 262144, 512, 32768);
    }

    // phase 3: GRU — MFMA, 128 blocks (8 XCD-confined bg x 16 unit-slices)
    zero_kernel<<<256, 256, 0, stream>>>((float*)hx, 65536);
    for (int l = 0; l < 2; l++) {
        const u16* Aseq = (l == 0) ? zp : h1bf;
        u16* seqOut = (l == 0) ? h1bf : h2bf;
        const u16* WiL = WiB + (long)l * 1536 * 512;
        const u16* WhL = WhB + (long)l * 1536 * 512;
        const float* biL = bi + (long)l * 1536;
        const float* bhL = bh + (long)l * 1536;
        for (int seg = 0; seg < 4; seg++) {
            gemm_nt<<<dim3(12, 64, 1), 256, 0, stream>>>(
                Aseq + (long)seg * 128 * 64 * 512, WiL, gi, 512, 512, 512, 1536,
                0, 0, 0, biL, nullptr, 1.f, 0);
            const float* giP = gi;
            u16* soP = seqOut;
            int s0v = seg * 128;
            int lv = l;
            void* args[] = { (void*)&giP, (void*)&WhL, (void*)&bhL, (void*)&soP,
                             (void*)&hx, (void*)&s0v, (void*)&lv };
            hipLaunchCooperativeKernel((void*)gru_mfma, dim3(128), dim3(256),
                                       args, 0, stream);
        }
    }

    final_kernel<<<8192, 256, 0, stream>>>(h2bf, Wf, bfin, out);
}